// Round 16
// baseline (266.807 us; speedup 1.0000x reference)
//
#include <hip/hip_runtime.h>
#include <stdint.h>
#include <math.h>

typedef float fx4 __attribute__((ext_vector_type(4)));
typedef float fx16 __attribute__((ext_vector_type(16)));
typedef int   ix4 __attribute__((ext_vector_type(4)));
typedef int   ix8 __attribute__((ext_vector_type(8)));

#define NB 4096
#define ND 1024
#define CEPS 1e-6f
#define CTHR 0.5f
#define NT16 16          // K-tiles of 64: 1024/64

// ---------- helpers ----------

__device__ __forceinline__ void gload16(const void* g, void* l) {
  __builtin_amdgcn_global_load_lds(
      (const __attribute__((address_space(1))) uint32_t*)(uintptr_t)g,
      (__attribute__((address_space(3))) uint32_t*)(uint32_t)(uintptr_t)l,
      16, 0, 0);
}

__device__ __forceinline__ ix8 ldfrag8(const char* p0, const char* p1) {
  const ix4 lo = *(const ix4*)p0;
  const ix4 hi = *(const ix4*)p1;
  ix8 r;
  r[0] = lo[0]; r[1] = lo[1]; r[2] = lo[2]; r[3] = lo[3];
  r[4] = hi[0]; r[5] = hi[1]; r[6] = hi[2]; r[7] = hi[3];
  return r;
}

// fp8 e4m3 (OCP on gfx950), scales = 127 (x1.0) — validated R4/R7-R14
#define MFMAS(A, B, C) \
  __builtin_amdgcn_mfma_scale_f32_32x32x64_f8f6f4((A), (B), (C), 0, 0, 0, 127, 0, 127)

// ---------- kernel 1: f32 -> fp8 convert + row norms (f32) ----------

__global__ __launch_bounds__(256) void cmc_convert(
    const float* __restrict__ in, uint8_t* __restrict__ xf8,
    float* __restrict__ lnorm) {
  const int row = blockIdx.x;           // 0 .. 3*4096-1
  const int tid = threadIdx.x;
  const fx4 v = *(const fx4*)(in + (size_t)row * ND + tid * 4);
  int pk = __builtin_amdgcn_cvt_pk_fp8_f32(v[0], v[1], 0, false);
  pk = __builtin_amdgcn_cvt_pk_fp8_f32(v[2], v[3], pk, true);
  ((int*)(xf8 + (size_t)row * ND))[tid] = pk;
  float ss = v[0]*v[0] + v[1]*v[1] + v[2]*v[2] + v[3]*v[3];
  #pragma unroll
  for (int d = 1; d < 64; d <<= 1) ss += __shfl_xor(ss, d);
  __shared__ float sred[4];
  if ((tid & 63) == 0) sred[tid >> 6] = ss;
  __syncthreads();
  if (tid == 0) lnorm[row] = sqrtf(sred[0] + sred[1] + sred[2] + sred[3]);
}

// ---------- 256x256 fp8 gram, BK=64, 8 waves (64x128 each), SINGLE-buffer ----------
// Traffic-reduction round: staged bytes per pair 786 MB -> 384 MB (each panel
// staged 16x not 32x); LDS reads 2.0 -> 1.5 KB per MFMA (fatter wave tiles).
// LDS 32 KiB: A [256 rows][64 B] @0, B @16384.
// Swizzle (64-B rows): stored_byte(r,c) = r*64 + (c ^ ((r&3)<<4)).
// Staging: linear dest (global_load_lds), source col pre-swizzled (rule #21);
// 4 passes of 8 KB (rows tid>>2 per half-panel).
// Resource audit (R11/R13 lesson): acc 128 + frags ~48 + addr ~25 ~= 200 VGPR;
// (512,2) cap = 512/2*... = 256 >= 200 with headroom; LDS 2x32 KiB; 1024 thr/CU.

__device__ __forceinline__ void gram256S(
    const uint8_t* __restrict__ Xi, const uint8_t* __restrict__ Xj,
    int rb, int cb, char* smem, int tid, fx16 (&acc)[2][4]) {
  const int l = tid & 63, w = tid >> 6;
  const int wr = w >> 1, wc = w & 1;     // wave grid 4x2, wave tile 64x128
  // staging: pass covers 8 KB = 128 rows x 64 B; row = tid>>2, stored col = (tid&3)*16
  const int srow = tid >> 2;             // 0..127
  const int scol = (((tid & 3) ^ (srow & 3)) << 4);  // pre-swizzled source col
  const uint8_t* gA = Xi + (size_t)(rb + srow) * ND + scol;
  const uint8_t* gB = Xj + (size_t)(cb + srow) * ND + scol;
  char* dA = smem + tid * 16;
  char* dB = smem + 16384 + tid * 16;

  // frag reads: row = base + (l&31); (row&3) == (l&3) for all frag bases
  const int swz = (l & 3) << 4;
  const int kb = (l >> 5) * 32;          // K sub-block
  const char* rdA = smem + (wr * 64 + (l & 31)) * 64;
  const char* rdB = smem + 16384 + (wc * 128 + (l & 31)) * 64;

  #pragma unroll
  for (int m = 0; m < 2; ++m)
    #pragma unroll
    for (int n = 0; n < 4; ++n)
      #pragma unroll
      for (int e = 0; e < 16; ++e) acc[m][n][e] = 0.f;

  #pragma unroll 1
  for (int t = 0; t < NT16; ++t) {
    const int k0 = t * 64;
    gload16(gA + k0, dA);                          // A rows 0..127
    gload16(gA + (size_t)128 * ND + k0, dA + 8192); // A rows 128..255
    gload16(gB + k0, dB);                          // B rows 0..127
    gload16(gB + (size_t)128 * ND + k0, dB + 8192); // B rows 128..255
    __syncthreads();                     // drain: tile landed (vmcnt(0)+barrier)
    const int c0 = kb ^ swz;
    const int c1 = (kb + 16) ^ swz;
    ix8 A[2], B[4];
    A[0] = ldfrag8(rdA + c0,        rdA + c1);
    A[1] = ldfrag8(rdA + 2048 + c0, rdA + 2048 + c1);   // +32 rows
    #pragma unroll
    for (int n = 0; n < 4; ++n)
      B[n] = ldfrag8(rdB + n * 2048 + c0, rdB + n * 2048 + c1);
    #pragma unroll
    for (int m = 0; m < 2; ++m)
      #pragma unroll
      for (int n = 0; n < 4; ++n)
        acc[m][n] = MFMAS(A[m], B[n], acc[m][n]);
    __syncthreads();                     // all reads consumed before restage
  }
}

// ---------- kernel 2: per-modal self-gram -> bitmask (COMPACT upper-tri grid) ----------
// 256x256 tiles: 136 upper-tri per modal x 3 = 408 = 8 x 51, XCD-swizzled.

__global__ __launch_bounds__(512, 2) void cmc_selfmask(
    const uint8_t* __restrict__ xf8, const float* __restrict__ lnorm,
    uint32_t* __restrict__ maskw) {
  __shared__ __align__(16) char smem[32768];
  const int o = blockIdx.x;              // 0..407
  const int bid = (o & 7) * 51 + (o >> 3);    // XCD-contiguous (408 % 8 == 0)
  const int md = bid / 136;
  int k = bid - md * 136;                // upper-tri tile index within modal
  int by = 0;
  while (k >= 16 - by) { k -= 16 - by; ++by; }   // uniform scalar decode
  const int bx = by + k;
  const int rb = by * 256, cb = bx * 256;
  const int tid = threadIdx.x;
  const int l = tid & 63, w = tid >> 6;
  const int wr = w >> 1, wc = w & 1;

  const uint8_t* X = xf8 + (size_t)md * NB * ND;
  fx16 acc[2][4];
  gram256S(X, X, rb, cb, smem, tid, acc);

  // threshold -> 256x256 bit tile in LDS (smem free after gram's final sync)
  uint32_t* tile = (uint32_t*)smem;      // [256][8] words = 8 KiB
  float* Lr = (float*)(smem + 8192);     // 256 f
  float* Lc = (float*)(smem + 9216);     // 256 f
  if (tid < 256) {
    Lr[tid] = lnorm[md * NB + rb + tid];
    Lc[tid] = lnorm[md * NB + cb + tid];
  }
  __syncthreads();

  #pragma unroll
  for (int m = 0; m < 2; ++m)
    #pragma unroll
    for (int r = 0; r < 16; ++r) {
      const int rl0 = wr * 64 + m * 32 + (r & 3) + 8 * (r >> 2);  // + 4*(l>>5)
      const float Lrv = Lr[rl0 + 4 * (l >> 5)];
      #pragma unroll
      for (int n = 0; n < 4; ++n) {
        const int cl = wc * 128 + n * 32 + (l & 31);
        const float cv = acc[m][n][r] / fmaxf(Lrv * Lc[cl], CEPS);
        const uint64_t b = __ballot(cv <= CTHR);
        if (l == 0)  tile[(rl0 + 0) * 8 + wc * 4 + n] = (uint32_t)b;
        if (l == 32) tile[(rl0 + 4) * 8 + wc * 4 + n] = (uint32_t)(b >> 32);
      }
    }
  __syncthreads();

  // direct region: rows [rb,+256) x words [cb/32,+8) — exclusively owned
  for (int t = tid; t < 2048; t += 512) {
    const int row = t >> 3, wd = t & 7;
    maskw[((size_t)md * NB + rb + row) * 128 + (cb >> 5) + wd] = tile[t];
  }
  // transposed region: rows [cb,+256) x words [rb/32,+8)
  if (by != bx) {
    for (int t = tid; t < 2048; t += 512) {
      const int crow = t & 255;
      const int wp = t >> 8;             // 0..7
      uint32_t wv = 0;
      #pragma unroll
      for (int r = 0; r < 32; ++r) {
        const uint32_t bit = (tile[(wp * 32 + r) * 8 + (crow >> 5)] >> (crow & 31)) & 1u;
        wv |= bit << r;
      }
      maskw[((size_t)md * NB + cb + crow) * 128 + (rb >> 5) + wp] = wv;
    }
  }
}

// ---------- kernel 3: per-pair cross gram + masked exp + count row-partials ----------
// 1D grid 768 = 8 x 96 with XCD swizzle (contiguous row-bands per XCD).

__global__ __launch_bounds__(512, 2) void cmc_pair(
    const uint8_t* __restrict__ xf8, const float* __restrict__ lnorm,
    const uint32_t* __restrict__ maskw,
    float* __restrict__ sumexp, float* __restrict__ cntrow,
    float* __restrict__ diagv) {
  __shared__ __align__(16) char smem[32768];
  const int o = blockIdx.x;              // 0..767
  const int bid = (o & 7) * 96 + (o >> 3);    // XCD-contiguous (768 % 8 == 0)
  const int p = bid >> 8;                // 256 tiles per pair
  const int rem = bid & 255;
  const int by = rem >> 4, bx = rem & 15;
  const int mi = (p == 2) ? 1 : 0;
  const int mj = (p == 0) ? 1 : 2;
  const int rb = by * 256, cb = bx * 256;
  const int tid = threadIdx.x;
  const int l = tid & 63, w = tid >> 6;
  const int wr = w >> 1, wc = w & 1;

  const uint8_t* Xi = xf8 + (size_t)mi * NB * ND;
  const uint8_t* Xj = xf8 + (size_t)mj * NB * ND;

  fx16 acc[2][4];
  gram256S(Xi, Xj, rb, cb, smem, tid, acc);

  // stage masks + norms into LDS (smem free after gram's final sync)
  uint32_t* Mt = (uint32_t*)smem;        // Mi [256][8] then Mj [256][8] = 16 KiB
  float* Lri = (float*)(smem + 16384);   // 256 f
  float* Lcj = (float*)(smem + 17408);   // 256 f
  for (int t = tid; t < 2048; t += 512) {
    const int row = t >> 3, wd = t & 7;
    Mt[t]        = maskw[((size_t)mi * NB + rb + row) * 128 + (cb >> 5) + wd];
    Mt[2048 + t] = maskw[((size_t)mj * NB + rb + row) * 128 + (cb >> 5) + wd];
  }
  if (tid < 256) {
    Lri[tid] = lnorm[mi * NB + rb + tid];
    Lcj[tid] = lnorm[mj * NB + cb + tid];
  }
  __syncthreads();

  #pragma unroll
  for (int m = 0; m < 2; ++m)
    #pragma unroll
    for (int r = 0; r < 16; ++r) {
      const int rl = wr * 64 + m * 32 + (r & 3) + 8 * (r >> 2) + 4 * (l >> 5);
      const int rg = rb + rl;
      const float Lrv = Lri[rl];
      float se = 0.f, ct = 0.f;
      #pragma unroll
      for (int n = 0; n < 4; ++n) {
        const int cl = wc * 128 + n * 32 + (l & 31);
        const int cg = cb + cl;
        const uint32_t bi = (Mt[rl * 8 + (cl >> 5)] >> (cl & 31)) & 1u;
        const uint32_t bj = (Mt[2048 + rl * 8 + (cl >> 5)] >> (cl & 31)) & 1u;
        const bool msk = bi | bj | (rg == cg);
        const float logit = acc[m][n][r] / fmaxf(Lrv * Lcj[cl], CEPS) * 10.0f;
        if (rg == cg) diagv[p * NB + rg] = logit;
        if (msk) { se += __expf(logit); ct += 1.f; }
      }
      #pragma unroll
      for (int d = 1; d < 32; d <<= 1) {
        se += __shfl_xor(se, d);
        ct += __shfl_xor(ct, d);
      }
      if ((l & 31) == 0) {
        atomicAdd(&sumexp[p * NB + rg], se);
        atomicAdd(&cntrow[p * NB + rg], ct);
      }
    }
}

// ---------- kernel 4: finalize ----------

__global__ __launch_bounds__(256) void cmc_final(
    const float* __restrict__ sumexp, const float* __restrict__ cntrow,
    const float* __restrict__ diagv, float* __restrict__ out) {
  const int tid = threadIdx.x;
  __shared__ float sred[8];
  float lsum = 0.f;
  for (int p = 0; p < 3; ++p) {
    float t = 0.f, c = 0.f;
    for (int r = tid; r < NB; r += 256) {
      const float cnt = cntrow[p * NB + r];
      if (cnt > 1.0f) {
        t += logf(sumexp[p * NB + r]) - diagv[p * NB + r];
        c += 1.f;
      }
    }
    #pragma unroll
    for (int d = 1; d < 64; d <<= 1) { t += __shfl_xor(t, d); c += __shfl_xor(c, d); }
    if ((tid & 63) == 0) { sred[(tid >> 6) * 2] = t; sred[(tid >> 6) * 2 + 1] = c; }
    __syncthreads();
    if (tid == 0) {
      const float tt = sred[0] + sred[2] + sred[4] + sred[6];
      const float cc = sred[1] + sred[3] + sred[5] + sred[7];
      lsum += (cc > 0.f) ? tt / fmaxf(cc, 1.f) : 0.f;
    }
    __syncthreads();
  }
  if (tid == 0) out[0] = lsum / 3.0f;
}

// ---------- launch ----------

extern "C" void kernel_launch(void* const* d_in, const int* in_sizes, int n_in,
                              void* d_out, int out_size, void* d_ws, size_t ws_size,
                              hipStream_t stream) {
  const float* in = (const float*)d_in[0];
  float* out = (float*)d_out;
  char* ws = (char*)d_ws;

  const size_t X8_BYTES = (size_t)3 * NB * ND;          // 12,582,912
  uint8_t* xf8  = (uint8_t*)ws;
  float* lnorm  = (float*)(ws + X8_BYTES);
  float* sumexp = lnorm + 3 * NB;
  float* cntrow = sumexp + 3 * NB;
  float* diagv  = cntrow + 3 * NB;
  uint32_t* maskw = (uint32_t*)(diagv + 3 * NB);        // [3][4096][128] = 6 MB

  // zero both atomically-accumulated buffers (sumexp ++ cntrow contiguous)
  hipMemsetAsync(sumexp, 0, (size_t)2 * 3 * NB * sizeof(float), stream);

  cmc_convert<<<3 * NB, 256, 0, stream>>>(in, xf8, lnorm);
  cmc_selfmask<<<408, 512, 0, stream>>>(xf8, lnorm, maskw);
  cmc_pair<<<768, 512, 0, stream>>>(xf8, lnorm, maskw, sumexp, cntrow, diagv);
  cmc_final<<<1, 256, 0, stream>>>(sumexp, cntrow, diagv, out);
}

// Round 17
// 201.025 us; speedup vs baseline: 1.3272x; 1.3272x over previous
//
#include <hip/hip_runtime.h>
#include <stdint.h>
#include <math.h>

typedef float fx4 __attribute__((ext_vector_type(4)));
typedef float fx16 __attribute__((ext_vector_type(16)));
typedef int   ix4 __attribute__((ext_vector_type(4)));
typedef int   ix8 __attribute__((ext_vector_type(8)));

#define NB 4096
#define ND 1024
#define CTHR 0.5f
#define NT8 8            // K-tiles of 128: 1024/128

// ---------- helpers ----------

__device__ __forceinline__ void gload16(const void* g, void* l) {
  __builtin_amdgcn_global_load_lds(
      (const __attribute__((address_space(1))) uint32_t*)(uintptr_t)g,
      (__attribute__((address_space(3))) uint32_t*)(uint32_t)(uintptr_t)l,
      16, 0, 0);
}

__device__ __forceinline__ ix8 ldfrag8(const char* p0, const char* p1) {
  const ix4 lo = *(const ix4*)p0;
  const ix4 hi = *(const ix4*)p1;
  ix8 r;
  r[0] = lo[0]; r[1] = lo[1]; r[2] = lo[2]; r[3] = lo[3];
  r[4] = hi[0]; r[5] = hi[1]; r[6] = hi[2]; r[7] = hi[3];
  return r;
}

// fp8 e4m3 (OCP on gfx950), scales = 127 (x1.0) — validated R4/R7-R15
#define MFMAS(A, B, C) \
  __builtin_amdgcn_mfma_scale_f32_32x32x64_f8f6f4((A), (B), (C), 0, 0, 0, 127, 0, 127)

// ---------- kernel 1: f32 -> fp8 convert + reciprocal row norms (f32) ----------
// Stores rnorm = 1/L. Valid vs ref's /max(Li*Lj,eps): L ~ 32 for 1024-d
// gaussian rows, so max() never binds and acc*rLi*rLj == acc/(Li*Lj).

__global__ __launch_bounds__(256) void cmc_convert(
    const float* __restrict__ in, uint8_t* __restrict__ xf8,
    float* __restrict__ rnorm) {
  const int row = blockIdx.x;           // 0 .. 3*4096-1
  const int tid = threadIdx.x;
  const fx4 v = *(const fx4*)(in + (size_t)row * ND + tid * 4);
  int pk = __builtin_amdgcn_cvt_pk_fp8_f32(v[0], v[1], 0, false);
  pk = __builtin_amdgcn_cvt_pk_fp8_f32(v[2], v[3], pk, true);
  ((int*)(xf8 + (size_t)row * ND))[tid] = pk;
  float ss = v[0]*v[0] + v[1]*v[1] + v[2]*v[2] + v[3]*v[3];
  #pragma unroll
  for (int d = 1; d < 64; d <<= 1) ss += __shfl_xor(ss, d);
  __shared__ float sred[4];
  if ((tid & 63) == 0) sred[tid >> 6] = ss;
  __syncthreads();
  if (tid == 0) rnorm[row] = 1.0f / sqrtf(sred[0] + sred[1] + sred[2] + sred[3]);
}

// ---------- 128x128 fp8 gram, BK=128, 2 waves (64x128 each), SINGLE-buffer ----------
// R8's gram128B — fastest measured pair core (119.8 us mean, R9 bench).
// LDS 32 KiB: A [128 rows][128 B] @0, B @16384.
// Swizzle: stored_byte(r,c) = r*128 + (c ^ ((r&7)<<4)); staging source col
// pre-swizzled (rule #21), global_load_lds dest linear.
// Resource audit: VGPR 108 measured, (128,2) cap 256 — 2.4x headroom;
// LDS 32 KiB -> 4 blocks/CU at 2 waves/EU.

__device__ __forceinline__ void gram128B(
    const uint8_t* __restrict__ Xi, const uint8_t* __restrict__ Xj,
    int rb, int cb, char* smem, int tid, fx16 (&acc)[2][4]) {
  const int l = tid & 63, w = tid >> 6;  // 2 waves: w = row half
  // staging: thread covers dest bytes chunk*2048 + tid*16; row=chunk*16+(tid>>3)
  const int srow = tid >> 3;             // 0..15
  const int scol = ((tid & 7) ^ (srow & 7)) << 4;   // pre-swizzled source col
  const uint8_t* gA = Xi + (size_t)(rb + srow) * ND + scol;
  const uint8_t* gB = Xj + (size_t)(cb + srow) * ND + scol;
  char* dA = smem + tid * 16;
  char* dB = smem + 16384 + tid * 16;

  // frag reads: row = (base) + (l&31); (row&7) == (l&7) for all frags
  const int swz = (l & 7) << 4;
  const int kb = (l >> 5) * 32;          // K sub-block within k-step
  const char* rdA = smem + (w * 64 + (l & 31)) * 128;
  const char* rdB = smem + 16384 + (l & 31) * 128;

  #pragma unroll
  for (int m = 0; m < 2; ++m)
    #pragma unroll
    for (int n = 0; n < 4; ++n)
      #pragma unroll
      for (int e = 0; e < 16; ++e) acc[m][n][e] = 0.f;

  #pragma unroll 1
  for (int t = 0; t < NT8; ++t) {
    const int k0 = t * 128;
    #pragma unroll
    for (int s = 0; s < 8; ++s) {
      gload16(gA + (size_t)s * 16 * ND + k0, dA + s * 2048);
      gload16(gB + (size_t)s * 16 * ND + k0, dB + s * 2048);
    }
    __syncthreads();                     // drain: tile landed
    #pragma unroll
    for (int ks = 0; ks < 2; ++ks) {
      const int c0 = (ks * 64 + kb) ^ swz;
      const int c1 = (ks * 64 + kb + 16) ^ swz;
      ix8 A[2], B[4];
      #pragma unroll
      for (int m = 0; m < 2; ++m)
        A[m] = ldfrag8(rdA + m * 4096 + c0, rdA + m * 4096 + c1);
      #pragma unroll
      for (int n = 0; n < 4; ++n)
        B[n] = ldfrag8(rdB + n * 4096 + c0, rdB + n * 4096 + c1);
      #pragma unroll
      for (int m = 0; m < 2; ++m)
        #pragma unroll
        for (int n = 0; n < 4; ++n)
          acc[m][n] = MFMAS(A[m], B[n], acc[m][n]);
    }
    __syncthreads();                     // all reads consumed before restage
  }
}

// ---------- kernel 2: per-modal self-gram -> bitmask (COMPACT upper-tri grid) ----------
// 1D grid 1584 = 3 modals x 528 upper-tri tiles = 8 x 198, XCD-swizzled.

__global__ __launch_bounds__(128, 2) void cmc_selfmask(
    const uint8_t* __restrict__ xf8, const float* __restrict__ rnorm,
    uint32_t* __restrict__ maskw) {
  __shared__ __align__(16) char smem[32768];
  const int o = blockIdx.x;              // 0..1583
  const int bid = (o & 7) * 198 + (o >> 3);   // XCD-contiguous (1584 % 8 == 0)
  const int md = bid / 528;
  int k = bid - md * 528;                // upper-tri tile index within modal
  int by = 0;
  while (k >= 32 - by) { k -= 32 - by; ++by; }   // uniform scalar decode
  const int bx = by + k;
  const int rb = by * 128, cb = bx * 128;
  const int tid = threadIdx.x;
  const int l = tid & 63, w = tid >> 6;

  const uint8_t* X = xf8 + (size_t)md * NB * ND;
  fx16 acc[2][4];
  gram128B(X, X, rb, cb, smem, tid, acc);

  // threshold -> 128x128 bit tile in LDS (smem free after gram's final sync)
  uint32_t* tile = (uint32_t*)smem;      // [128][4] words = 2 KiB
  float* Rr = (float*)(smem + 2048);
  float* Rc = (float*)(smem + 2560);
  if (tid < 128) {
    Rr[tid] = rnorm[md * NB + rb + tid];
    Rc[tid] = rnorm[md * NB + cb + tid];
  }
  __syncthreads();

  #pragma unroll
  for (int m = 0; m < 2; ++m)
    #pragma unroll
    for (int r = 0; r < 16; ++r) {
      const int rl0 = w * 64 + m * 32 + (r & 3) + 8 * (r >> 2);  // + 4*(l>>5)
      const float Rrv = Rr[rl0 + 4 * (l >> 5)];
      #pragma unroll
      for (int n = 0; n < 4; ++n) {
        const int cl = n * 32 + (l & 31);
        const float cv = acc[m][n][r] * Rrv * Rc[cl];
        const uint64_t b = __ballot(cv <= CTHR);
        if (l == 0)  tile[(rl0 + 0) * 4 + n] = (uint32_t)b;
        if (l == 32) tile[(rl0 + 4) * 4 + n] = (uint32_t)(b >> 32);
      }
    }
  __syncthreads();

  // direct region: rows [rb,+128) x words [cb/32,+4) — exclusively owned
  for (int t = tid; t < 512; t += 128) {
    const int row = t >> 2, wd = t & 3;
    maskw[((size_t)md * NB + rb + row) * 128 + (cb >> 5) + wd] = tile[t];
  }
  // transposed region: rows [cb,+128) x words [rb/32,+4)
  if (by != bx) {
    for (int t = tid; t < 512; t += 128) {
      const int crow = t & 127;
      const int wp = t >> 7;
      uint32_t wv = 0;
      #pragma unroll
      for (int r = 0; r < 32; ++r) {
        const uint32_t bit = (tile[(wp * 32 + r) * 4 + (crow >> 5)] >> (crow & 31)) & 1u;
        wv |= bit << r;
      }
      maskw[((size_t)md * NB + cb + crow) * 128 + (rb >> 5) + wp] = wv;
    }
  }
}

// ---------- kernel 3: per-pair cross gram + masked exp + count row-partials ----------
// 1D grid 3072 = 8 x 384 with XCD swizzle: each XCD owns one pair's contiguous
// row-band -> Xi band (1.5MB) + Xj (4MB) ~ its L2 (R10: FETCH 104->73 MB).

__global__ __launch_bounds__(128, 2) void cmc_pair(
    const uint8_t* __restrict__ xf8, const float* __restrict__ rnorm,
    const uint32_t* __restrict__ maskw,
    float* __restrict__ sumexp, float* __restrict__ cntrow,
    float* __restrict__ diagv) {
  __shared__ __align__(16) char smem[32768];
  const int o = blockIdx.x;              // 0..3071
  const int bid = (o & 7) * 384 + (o >> 3);   // XCD-contiguous (3072 % 8 == 0)
  const int p = bid >> 10;               // pair: 0->(0,1) 1->(0,2) 2->(1,2)
  const int rem = bid & 1023;
  const int by = rem >> 5, bx = rem & 31;
  const int mi = (p == 2) ? 1 : 0;
  const int mj = (p == 0) ? 1 : 2;
  const int rb = by * 128, cb = bx * 128;
  const int tid = threadIdx.x;
  const int l = tid & 63, w = tid >> 6;

  const uint8_t* Xi = xf8 + (size_t)mi * NB * ND;
  const uint8_t* Xj = xf8 + (size_t)mj * NB * ND;

  fx16 acc[2][4];
  gram128B(Xi, Xj, rb, cb, smem, tid, acc);

  // stage masks + reciprocal norms into LDS (smem free after gram's final sync)
  uint32_t* Mt = (uint32_t*)smem;        // Mi [128][4] then Mj [128][4]
  float* Rri = (float*)(smem + 4096);
  float* Rcj = (float*)(smem + 4608);
  for (int t = tid; t < 512; t += 128) {
    const int row = t >> 2, wd = t & 3;
    Mt[t]       = maskw[((size_t)mi * NB + rb + row) * 128 + (cb >> 5) + wd];
    Mt[512 + t] = maskw[((size_t)mj * NB + rb + row) * 128 + (cb >> 5) + wd];
  }
  if (tid < 128) {
    Rri[tid] = rnorm[mi * NB + rb + tid];
    Rcj[tid] = rnorm[mj * NB + cb + tid];
  }
  __syncthreads();

  #pragma unroll
  for (int m = 0; m < 2; ++m)
    #pragma unroll
    for (int r = 0; r < 16; ++r) {
      const int rl = w * 64 + m * 32 + (r & 3) + 8 * (r >> 2) + 4 * (l >> 5);
      const int rg = rb + rl;
      const float Rrv = Rri[rl] * 10.0f;   // fold 1/temp
      float se = 0.f, ct = 0.f;
      #pragma unroll
      for (int n = 0; n < 4; ++n) {
        const int cl = n * 32 + (l & 31);
        const int cg = cb + cl;
        const uint32_t bi = (Mt[rl * 4 + (cl >> 5)] >> (cl & 31)) & 1u;
        const uint32_t bj = (Mt[512 + rl * 4 + (cl >> 5)] >> (cl & 31)) & 1u;
        const bool msk = bi | bj | (rg == cg);
        const float logit = acc[m][n][r] * Rrv * Rcj[cl];
        if (rg == cg) diagv[p * NB + rg] = logit;
        if (msk) { se += __expf(logit); ct += 1.f; }
      }
      #pragma unroll
      for (int d = 1; d < 32; d <<= 1) {
        se += __shfl_xor(se, d);
        ct += __shfl_xor(ct, d);
      }
      if ((l & 31) == 0) {
        atomicAdd(&sumexp[p * NB + rg], se);
        atomicAdd(&cntrow[p * NB + rg], ct);
      }
    }
}

// ---------- kernel 4: finalize ----------

__global__ __launch_bounds__(256) void cmc_final(
    const float* __restrict__ sumexp, const float* __restrict__ cntrow,
    const float* __restrict__ diagv, float* __restrict__ out) {
  const int tid = threadIdx.x;
  __shared__ float sred[8];
  float lsum = 0.f;
  for (int p = 0; p < 3; ++p) {
    float t = 0.f, c = 0.f;
    for (int r = tid; r < NB; r += 256) {
      const float cnt = cntrow[p * NB + r];
      if (cnt > 1.0f) {
        t += logf(sumexp[p * NB + r]) - diagv[p * NB + r];
        c += 1.f;
      }
    }
    #pragma unroll
    for (int d = 1; d < 64; d <<= 1) { t += __shfl_xor(t, d); c += __shfl_xor(c, d); }
    if ((tid & 63) == 0) { sred[(tid >> 6) * 2] = t; sred[(tid >> 6) * 2 + 1] = c; }
    __syncthreads();
    if (tid == 0) {
      const float tt = sred[0] + sred[2] + sred[4] + sred[6];
      const float cc = sred[1] + sred[3] + sred[5] + sred[7];
      lsum += (cc > 0.f) ? tt / fmaxf(cc, 1.f) : 0.f;
    }
    __syncthreads();
  }
  if (tid == 0) out[0] = lsum / 3.0f;
}

// ---------- launch ----------

extern "C" void kernel_launch(void* const* d_in, const int* in_sizes, int n_in,
                              void* d_out, int out_size, void* d_ws, size_t ws_size,
                              hipStream_t stream) {
  const float* in = (const float*)d_in[0];
  float* out = (float*)d_out;
  char* ws = (char*)d_ws;

  const size_t X8_BYTES = (size_t)3 * NB * ND;          // 12,582,912
  uint8_t* xf8  = (uint8_t*)ws;
  float* rnorm  = (float*)(ws + X8_BYTES);
  float* sumexp = rnorm + 3 * NB;
  float* cntrow = sumexp + 3 * NB;
  float* diagv  = cntrow + 3 * NB;
  uint32_t* maskw = (uint32_t*)(diagv + 3 * NB);        // [3][4096][128] = 6 MB

  // zero both atomically-accumulated buffers (sumexp ++ cntrow contiguous)
  hipMemsetAsync(sumexp, 0, (size_t)2 * 3 * NB * sizeof(float), stream);

  cmc_convert<<<3 * NB, 256, 0, stream>>>(in, xf8, rnorm);
  cmc_selfmask<<<1584, 128, 0, stream>>>(xf8, rnorm, maskw);
  cmc_pair<<<3072, 128, 0, stream>>>(xf8, rnorm, maskw, sumexp, cntrow, diagv);
  cmc_final<<<1, 256, 0, stream>>>(sumexp, cntrow, diagv, out);
}

// Round 18
// 196.044 us; speedup vs baseline: 1.3610x; 1.0254x over previous
//
#include <hip/hip_runtime.h>
#include <stdint.h>
#include <math.h>

typedef float fx4 __attribute__((ext_vector_type(4)));
typedef float fx16 __attribute__((ext_vector_type(16)));
typedef int   ix4 __attribute__((ext_vector_type(4)));
typedef int   ix8 __attribute__((ext_vector_type(8)));

#define NB 4096
#define ND 1024
#define CTHR 0.5f
#define NT8 8            // K-tiles of 128: 1024/128

// ---------- helpers ----------

__device__ __forceinline__ void gload16(const void* g, void* l) {
  __builtin_amdgcn_global_load_lds(
      (const __attribute__((address_space(1))) uint32_t*)(uintptr_t)g,
      (__attribute__((address_space(3))) uint32_t*)(uint32_t)(uintptr_t)l,
      16, 0, 0);
}

__device__ __forceinline__ ix8 ldfrag8(const char* p0, const char* p1) {
  const ix4 lo = *(const ix4*)p0;
  const ix4 hi = *(const ix4*)p1;
  ix8 r;
  r[0] = lo[0]; r[1] = lo[1]; r[2] = lo[2]; r[3] = lo[3];
  r[4] = hi[0]; r[5] = hi[1]; r[6] = hi[2]; r[7] = hi[3];
  return r;
}

// fp8 e4m3 (OCP on gfx950), scales = 127 (x1.0) — validated R4/R7-R16
#define MFMAS(A, B, C) \
  __builtin_amdgcn_mfma_scale_f32_32x32x64_f8f6f4((A), (B), (C), 0, 0, 0, 127, 0, 127)

// ---------- kernel 1: f32 -> fp8 convert + reciprocal row norms + zero accum ----------
// Stores rnorm = 1/L (L ~ 32 for 1024-d gaussian rows: eps never binds).
// Blocks 0..95 also zero sumexp++cntrow (24576 floats) — replaces memset dispatch.

__global__ __launch_bounds__(256) void cmc_convert(
    const float* __restrict__ in, uint8_t* __restrict__ xf8,
    float* __restrict__ rnorm, float* __restrict__ zacc) {
  const int row = blockIdx.x;           // 0 .. 3*4096-1
  const int tid = threadIdx.x;
  if (row < 96) zacc[row * 256 + tid] = 0.f;   // 96*256 = 24576 = 2*3*4096
  const fx4 v = *(const fx4*)(in + (size_t)row * ND + tid * 4);
  int pk = __builtin_amdgcn_cvt_pk_fp8_f32(v[0], v[1], 0, false);
  pk = __builtin_amdgcn_cvt_pk_fp8_f32(v[2], v[3], pk, true);
  ((int*)(xf8 + (size_t)row * ND))[tid] = pk;
  float ss = v[0]*v[0] + v[1]*v[1] + v[2]*v[2] + v[3]*v[3];
  #pragma unroll
  for (int d = 1; d < 64; d <<= 1) ss += __shfl_xor(ss, d);
  __shared__ float sred[4];
  if ((tid & 63) == 0) sred[tid >> 6] = ss;
  __syncthreads();
  if (tid == 0) rnorm[row] = 1.0f / sqrtf(sred[0] + sred[1] + sred[2] + sred[3]);
}

// ---------- 128x128 fp8 gram, BK=128, 2 waves (64x128 each), SINGLE-buffer ----------
// R8/R16 gram128B — fastest measured pair core (111 us, R17 bench of R16).
// LDS 32 KiB: A [128 rows][128 B] @0, B @16384.
// Swizzle: stored_byte(r,c) = r*128 + (c ^ ((r&7)<<4)); staging source col
// pre-swizzled (rule #21), global_load_lds dest linear.
// Resource audit: VGPR 108 measured, (128,2) cap 256 — 2.4x headroom.

__device__ __forceinline__ void gram128B(
    const uint8_t* __restrict__ Xi, const uint8_t* __restrict__ Xj,
    int rb, int cb, char* smem, int tid, fx16 (&acc)[2][4]) {
  const int l = tid & 63, w = tid >> 6;  // 2 waves: w = row half
  const int srow = tid >> 3;             // 0..15
  const int scol = ((tid & 7) ^ (srow & 7)) << 4;   // pre-swizzled source col
  const uint8_t* gA = Xi + (size_t)(rb + srow) * ND + scol;
  const uint8_t* gB = Xj + (size_t)(cb + srow) * ND + scol;
  char* dA = smem + tid * 16;
  char* dB = smem + 16384 + tid * 16;

  const int swz = (l & 7) << 4;
  const int kb = (l >> 5) * 32;          // K sub-block within k-step
  const char* rdA = smem + (w * 64 + (l & 31)) * 128;
  const char* rdB = smem + 16384 + (l & 31) * 128;

  #pragma unroll
  for (int m = 0; m < 2; ++m)
    #pragma unroll
    for (int n = 0; n < 4; ++n)
      #pragma unroll
      for (int e = 0; e < 16; ++e) acc[m][n][e] = 0.f;

  #pragma unroll 1
  for (int t = 0; t < NT8; ++t) {
    const int k0 = t * 128;
    #pragma unroll
    for (int s = 0; s < 8; ++s) {
      gload16(gA + (size_t)s * 16 * ND + k0, dA + s * 2048);
      gload16(gB + (size_t)s * 16 * ND + k0, dB + s * 2048);
    }
    __syncthreads();                     // drain: tile landed
    #pragma unroll
    for (int ks = 0; ks < 2; ++ks) {
      const int c0 = (ks * 64 + kb) ^ swz;
      const int c1 = (ks * 64 + kb + 16) ^ swz;
      ix8 A[2], B[4];
      #pragma unroll
      for (int m = 0; m < 2; ++m)
        A[m] = ldfrag8(rdA + m * 4096 + c0, rdA + m * 4096 + c1);
      #pragma unroll
      for (int n = 0; n < 4; ++n)
        B[n] = ldfrag8(rdB + n * 4096 + c0, rdB + n * 4096 + c1);
      #pragma unroll
      for (int m = 0; m < 2; ++m)
        #pragma unroll
        for (int n = 0; n < 4; ++n)
          acc[m][n] = MFMAS(A[m], B[n], acc[m][n]);
    }
    __syncthreads();                     // all reads consumed before restage
  }
}

// ---------- kernel 2: per-modal self-gram -> bitmask (COMPACT upper-tri grid) ----------
// 1D grid 1584 = 3 modals x 528 upper-tri tiles = 8 x 198, XCD-swizzled.

__global__ __launch_bounds__(128, 2) void cmc_selfmask(
    const uint8_t* __restrict__ xf8, const float* __restrict__ rnorm,
    uint32_t* __restrict__ maskw) {
  __shared__ __align__(16) char smem[32768];
  const int o = blockIdx.x;              // 0..1583
  const int bid = (o & 7) * 198 + (o >> 3);   // XCD-contiguous (1584 % 8 == 0)
  const int md = bid / 528;
  int k = bid - md * 528;                // upper-tri tile index within modal
  int by = 0;
  while (k >= 32 - by) { k -= 32 - by; ++by; }   // uniform scalar decode
  const int bx = by + k;
  const int rb = by * 128, cb = bx * 128;
  const int tid = threadIdx.x;
  const int l = tid & 63, w = tid >> 6;

  const uint8_t* X = xf8 + (size_t)md * NB * ND;
  fx16 acc[2][4];
  gram128B(X, X, rb, cb, smem, tid, acc);

  // threshold -> 128x128 bit tile in LDS (smem free after gram's final sync)
  uint32_t* tile = (uint32_t*)smem;      // [128][4] words = 2 KiB
  float* Rr = (float*)(smem + 2048);
  float* Rc = (float*)(smem + 2560);
  if (tid < 128) {
    Rr[tid] = rnorm[md * NB + rb + tid];
    Rc[tid] = rnorm[md * NB + cb + tid];
  }
  __syncthreads();

  #pragma unroll
  for (int m = 0; m < 2; ++m)
    #pragma unroll
    for (int r = 0; r < 16; ++r) {
      const int rl0 = w * 64 + m * 32 + (r & 3) + 8 * (r >> 2);  // + 4*(l>>5)
      const float Rrv = Rr[rl0 + 4 * (l >> 5)];
      #pragma unroll
      for (int n = 0; n < 4; ++n) {
        const int cl = n * 32 + (l & 31);
        const float cv = acc[m][n][r] * Rrv * Rc[cl];
        const uint64_t b = __ballot(cv <= CTHR);
        if (l == 0)  tile[(rl0 + 0) * 4 + n] = (uint32_t)b;
        if (l == 32) tile[(rl0 + 4) * 4 + n] = (uint32_t)(b >> 32);
      }
    }
  __syncthreads();

  // direct region: rows [rb,+128) x words [cb/32,+4) — exclusively owned
  for (int t = tid; t < 512; t += 128) {
    const int row = t >> 2, wd = t & 3;
    maskw[((size_t)md * NB + rb + row) * 128 + (cb >> 5) + wd] = tile[t];
  }
  // transposed region: rows [cb,+128) x words [rb/32,+4)
  if (by != bx) {
    for (int t = tid; t < 512; t += 128) {
      const int crow = t & 127;
      const int wp = t >> 7;
      uint32_t wv = 0;
      #pragma unroll
      for (int r = 0; r < 32; ++r) {
        const uint32_t bit = (tile[(wp * 32 + r) * 4 + (crow >> 5)] >> (crow & 31)) & 1u;
        wv |= bit << r;
      }
      maskw[((size_t)md * NB + cb + crow) * 128 + (rb >> 5) + wp] = wv;
    }
  }
}

// ---------- kernel 3: per-pair cross gram + masked exp + count row-partials ----------
// 1D grid 3072 = 8 x 384 with XCD swizzle: each XCD owns one pair's contiguous
// row-band (R10: FETCH 104->73 MB). Count via ballot+popc (saves the ct
// shuffle chain; 5 shuffle+add levels now carry se only).

__global__ __launch_bounds__(128, 2) void cmc_pair(
    const uint8_t* __restrict__ xf8, const float* __restrict__ rnorm,
    const uint32_t* __restrict__ maskw,
    float* __restrict__ sumexp, float* __restrict__ cntrow,
    float* __restrict__ diagv) {
  __shared__ __align__(16) char smem[32768];
  const int o = blockIdx.x;              // 0..3071
  const int bid = (o & 7) * 384 + (o >> 3);   // XCD-contiguous (3072 % 8 == 0)
  const int p = bid >> 10;               // pair: 0->(0,1) 1->(0,2) 2->(1,2)
  const int rem = bid & 1023;
  const int by = rem >> 5, bx = rem & 31;
  const int mi = (p == 2) ? 1 : 0;
  const int mj = (p == 0) ? 1 : 2;
  const int rb = by * 128, cb = bx * 128;
  const int tid = threadIdx.x;
  const int l = tid & 63, w = tid >> 6;

  const uint8_t* Xi = xf8 + (size_t)mi * NB * ND;
  const uint8_t* Xj = xf8 + (size_t)mj * NB * ND;

  fx16 acc[2][4];
  gram128B(Xi, Xj, rb, cb, smem, tid, acc);

  // stage masks + reciprocal norms into LDS (smem free after gram's final sync)
  uint32_t* Mt = (uint32_t*)smem;        // Mi [128][4] then Mj [128][4]
  float* Rri = (float*)(smem + 4096);
  float* Rcj = (float*)(smem + 4608);
  for (int t = tid; t < 512; t += 128) {
    const int row = t >> 2, wd = t & 3;
    Mt[t]       = maskw[((size_t)mi * NB + rb + row) * 128 + (cb >> 5) + wd];
    Mt[512 + t] = maskw[((size_t)mj * NB + rb + row) * 128 + (cb >> 5) + wd];
  }
  if (tid < 128) {
    Rri[tid] = rnorm[mi * NB + rb + tid];
    Rcj[tid] = rnorm[mj * NB + cb + tid];
  }
  __syncthreads();

  #pragma unroll
  for (int m = 0; m < 2; ++m)
    #pragma unroll
    for (int r = 0; r < 16; ++r) {
      const int rl = w * 64 + m * 32 + (r & 3) + 8 * (r >> 2) + 4 * (l >> 5);
      const int rg = rb + rl;
      const float Rrv = Rri[rl] * 10.0f;   // fold 1/temp
      float se = 0.f;
      uint64_t bm[4];
      #pragma unroll
      for (int n = 0; n < 4; ++n) {
        const int cl = n * 32 + (l & 31);
        const int cg = cb + cl;
        const uint32_t bi = (Mt[rl * 4 + (cl >> 5)] >> (cl & 31)) & 1u;
        const uint32_t bj = (Mt[512 + rl * 4 + (cl >> 5)] >> (cl & 31)) & 1u;
        const bool msk = bi | bj | (rg == cg);
        const float logit = acc[m][n][r] * Rrv * Rcj[cl];
        if (rg == cg) diagv[p * NB + rg] = logit;
        bm[n] = __ballot(msk);
        if (msk) se += __expf(logit);
      }
      #pragma unroll
      for (int d = 1; d < 32; d <<= 1) se += __shfl_xor(se, d);
      if ((l & 31) == 0) {
        // my half of each ballot = counts for MY row rg
        int ct = 0;
        #pragma unroll
        for (int n = 0; n < 4; ++n)
          ct += __popc((uint32_t)(bm[n] >> (l & 32)));
        atomicAdd(&sumexp[p * NB + rg], se);
        atomicAdd(&cntrow[p * NB + rg], (float)ct);
      }
    }
}

// ---------- kernel 4: finalize ----------

__global__ __launch_bounds__(256) void cmc_final(
    const float* __restrict__ sumexp, const float* __restrict__ cntrow,
    const float* __restrict__ diagv, float* __restrict__ out) {
  const int tid = threadIdx.x;
  __shared__ float sred[8];
  float lsum = 0.f;
  for (int p = 0; p < 3; ++p) {
    float t = 0.f, c = 0.f;
    for (int r = tid; r < NB; r += 256) {
      const float cnt = cntrow[p * NB + r];
      if (cnt > 1.0f) {
        t += logf(sumexp[p * NB + r]) - diagv[p * NB + r];
        c += 1.f;
      }
    }
    #pragma unroll
    for (int d = 1; d < 64; d <<= 1) { t += __shfl_xor(t, d); c += __shfl_xor(c, d); }
    if ((tid & 63) == 0) { sred[(tid >> 6) * 2] = t; sred[(tid >> 6) * 2 + 1] = c; }
    __syncthreads();
    if (tid == 0) {
      const float tt = sred[0] + sred[2] + sred[4] + sred[6];
      const float cc = sred[1] + sred[3] + sred[5] + sred[7];
      lsum += (cc > 0.f) ? tt / fmaxf(cc, 1.f) : 0.f;
    }
    __syncthreads();
  }
  if (tid == 0) out[0] = lsum / 3.0f;
}

// ---------- launch ----------

extern "C" void kernel_launch(void* const* d_in, const int* in_sizes, int n_in,
                              void* d_out, int out_size, void* d_ws, size_t ws_size,
                              hipStream_t stream) {
  const float* in = (const float*)d_in[0];
  float* out = (float*)d_out;
  char* ws = (char*)d_ws;

  const size_t X8_BYTES = (size_t)3 * NB * ND;          // 12,582,912
  uint8_t* xf8  = (uint8_t*)ws;
  float* rnorm  = (float*)(ws + X8_BYTES);
  float* sumexp = rnorm + 3 * NB;
  float* cntrow = sumexp + 3 * NB;
  float* diagv  = cntrow + 3 * NB;
  uint32_t* maskw = (uint32_t*)(diagv + 3 * NB);        // [3][4096][128] = 6 MB

  // sumexp ++ cntrow zeroed inside cmc_convert (blocks 0..95) — no memset.
  cmc_convert<<<3 * NB, 256, 0, stream>>>(in, xf8, rnorm, sumexp);
  cmc_selfmask<<<1584, 128, 0, stream>>>(xf8, rnorm, maskw);
  cmc_pair<<<3072, 128, 0, stream>>>(xf8, rnorm, maskw, sumexp, cntrow, diagv);
  cmc_final<<<1, 256, 0, stream>>>(sumexp, cntrow, diagv, out);
}